// Round 4
// baseline (7622.475 us; speedup 1.0000x reference)
//
#include <hip/hip_runtime.h>

// ---------------------------------------------------------------------------
// 3-layer LSTM (B=64, T=512, IN=128, H=1024) + final FC, persistent kernel.
//
// R4 = R2's proven envelope (192 blocks x 256 thr, 1/CU, identical ws layout)
//      + per-layer dataflow flags instead of the global barrier
//      + 7-deep chunk-load pipeline (R2 was 1-deep: 16 x ~650cy serialized).
//  - Block (layer, grp): 16 hid x 4 gates, full K (ih + hh folded), 4-wave
//    K-split, fp16 MFMA A-frags in registers, c-state fp32 in registers.
//  - hbuf ring depth 2 (= R2 parity buf). Flags: hslot[layer*64+grp] = t+1.
//    W1 own>=t (waves 2,3), W2 feed>=t+1 (waves 0,1; layer>=1),
//    W3 ring guard next-layer>=t-1 (waves 2,3; layer<=1).
//  - All hbuf traffic RELAXED agent-scope 8B atomics (IC-coherent, no cache
//    maintenance ops). Flag store after s_waitcnt(0)+syncthreads (R2-proven).
// ---------------------------------------------------------------------------

#define TT 512
#define INF 128
#define HH 1024
#define NBLOCKS 192
#define DPTH 7

typedef _Float16 f16x8 __attribute__((ext_vector_type(8)));
typedef float f32x4 __attribute__((ext_vector_type(4)));

// ws layout (bytes) — byte-identical footprint to R2 (9,176,064 B proven):
//   0      : hslot[3*64] int (+pad to 1 KB)
//   1024   : hbuf  3 rings x 2 slots x 32 kk x 4 bt x 64 lane x 8 f16 = 786432
//   787456 : xbuf  512 t x 4 kk x 4 bt x 64 lane x 8 f16 = 8388608
#define HSLOT_OFF 0
#define HBUF_OFF 1024
#define XBUF_OFF (1024 + 786432)

__device__ __forceinline__ float sigmf(float x) { return 1.f / (1.f + __expf(-x)); }
__device__ __forceinline__ float tanhfast(float x) { return 1.f - 2.f / (__expf(2.f * x) + 1.f); }

__global__ void init_kernel(unsigned* ws_u32, float* out, const float* fcb) {
  int tid = blockIdx.x * 256 + threadIdx.x;
  if (tid < 196864) ws_u32[tid] = 0u;  // flags (256 u32) + hbuf (196608 u32)
  if (blockIdx.x == 0 && threadIdx.x < 64) out[threadIdx.x] = fcb[0];
}

// Pack x[b][t][k] (fp32) -> fp16 B-fragment layout [t][kk][bt][lane][8]
__global__ void packx_kernel(const float* __restrict__ x, _Float16* __restrict__ xbuf) {
  int tid = blockIdx.x * 256 + threadIdx.x; // [0, 524288)
  int t = tid >> 10;
  int rem = tid & 1023;
  int kk = rem >> 8;
  int bt = (rem >> 6) & 3;
  int lane = rem & 63;
  int b = bt * 16 + (lane & 15);
  int k = kk * 32 + (lane >> 4) * 8;
  const float* src = x + ((size_t)b * TT + t) * INF + k;
  f16x8 v;
#pragma unroll
  for (int j = 0; j < 8; ++j) v[j] = (_Float16)src[j];
  ((f16x8*)xbuf)[tid] = v;
}

// Agent-coherent (IC-level) 16B fragment load as two relaxed 8B atomics.
__device__ __forceinline__ f16x8 load_frag_agent(const unsigned long long* p) {
  union { unsigned long long u[2]; f16x8 v; } r;
  r.u[0] = __hip_atomic_load(p, __ATOMIC_RELAXED, __HIP_MEMORY_SCOPE_AGENT);
  r.u[1] = __hip_atomic_load(p + 1, __ATOMIC_RELAXED, __HIP_MEMORY_SCOPE_AGENT);
  return r.v;
}

__global__ void __launch_bounds__(256, 1)
lstm_main(const float* __restrict__ Wih0, const float* __restrict__ Wih1,
          const float* __restrict__ Wih2, const float* __restrict__ Whh,
          const float* __restrict__ bih, const float* __restrict__ bhh,
          const float* __restrict__ fcw, float* __restrict__ out,
          int* __restrict__ hslot, _Float16* __restrict__ hbuf,
          const _Float16* __restrict__ xbuf) {
  const int blk = blockIdx.x;
  const int layer = blk >> 6;
  const int grp = blk & 63;
  const int tid = threadIdx.x;
  const int wave = tid >> 6;
  const int lane = tid & 63;
  const int m = lane & 15;   // A-frag row within 16 (j); D col (batch within 16)
  const int q = lane >> 4;   // k-quad
  const int hid0 = grp << 4;

  const int KW = (layer == 0) ? 9 : 16;  // kk chunks per wave
  const int kk0 = wave * KW;

  __shared__ float part[4][4][16][66];  // [wave][gate][j][batch] (+2 pad)
  __shared__ float fcacc[64];

  // ---- one-time: weights -> fp16 A-fragments in registers (R2-verified) ----
  f16x8 afrag[4][16];
#pragma unroll
  for (int g = 0; g < 4; ++g) {
#pragma unroll
    for (int c = 0; c < 16; ++c) {
      if (c < KW) {
        int kk = kk0 + c;
        int row = g * HH + hid0 + m;
        const float* src;
        if (layer == 0) {
          src = (kk < 4) ? (Wih0 + (size_t)row * INF + kk * 32)
                         : (Whh + (size_t)row * HH + (kk - 4) * 32);
        } else if (layer == 1) {
          src = (kk < 32) ? (Wih1 + (size_t)row * HH + kk * 32)
                          : (Whh + (size_t)(4 * HH) * HH + (size_t)row * HH + (kk - 32) * 32);
        } else {
          src = (kk < 32) ? (Wih2 + (size_t)row * HH + kk * 32)
                          : (Whh + (size_t)(8 * HH) * HH + (size_t)row * HH + (kk - 32) * 32);
        }
        src += q * 8;
        f16x8 v;
#pragma unroll
        for (int j = 0; j < 8; ++j) v[j] = (_Float16)src[j];
        afrag[g][c] = v;
      }
    }
  }

  // ---- combine mapping: thread -> (batch bq, j = j4 + i) ----
  const int bq = tid & 63;
  const int j4 = wave * 4;
  float biasv[4][4];
#pragma unroll
  for (int g = 0; g < 4; ++g)
#pragma unroll
    for (int i = 0; i < 4; ++i) {
      int row = layer * 4 * HH + g * HH + hid0 + j4 + i;
      biasv[g][i] = bih[row] + bhh[row];
    }
  float fcwv[4];
#pragma unroll
  for (int i = 0; i < 4; ++i) fcwv[i] = (layer == 2) ? fcw[hid0 + j4 + i] : 0.f;
  float cst[4] = {0.f, 0.f, 0.f, 0.f};

  // publish address pieces: h value (b=bq, j=hid0+j4+i)
  const int jg = hid0 + j4;
  const int kkp = jg >> 5;
  const int qp = (jg >> 3) & 3;
  const int slot8 = wave & 1;
  const int btp = bq >> 4;
  const int lanep = (bq & 15) + (qp << 4);

  // poll roles (uniform per wave):
  //  waves 2,3: own-layer flag (W1) + ring guard (W3). waves 0,1: feed (W2).
  //  layer 0: all waves read hh -> all need W1; no W2 (x always ready).
  bool n1, n2, n3;
  if (layer == 0) { n1 = true; n2 = false; n3 = (wave >= 2); }
  else            { n1 = (wave >= 2); n2 = (wave < 2); n3 = (wave >= 2) && (layer == 1); }
  const int s1 = layer * 64 + lane;
  const int s2 = (layer - 1) * 64 + lane;
  const int s3 = (layer + 1) * 64 + lane;

  const f16x8* xb8 = (const f16x8*)xbuf;
  const unsigned long long* hb_u = (const unsigned long long*)hbuf;
  unsigned long long* hb_w = (unsigned long long*)hbuf;
  const f32x4 zacc = {0.f, 0.f, 0.f, 0.f};

  for (int t = 0; t < TT; ++t) {
    // ---------------- dataflow wait (per-wave, coalesced 64-slot polls) ----
    {
      const bool need1 = n1 && (t >= 1);
      const bool need2 = n2;
      const bool need3 = n3 && (t >= 2);
      if (need1 | need2 | need3) {
        bool ok = false;
        while (!ok) {
          bool g = true;
          if (need1)
            g &= (__hip_atomic_load(&hslot[s1], __ATOMIC_RELAXED,
                                    __HIP_MEMORY_SCOPE_AGENT) >= t);
          if (need2)
            g &= (__hip_atomic_load(&hslot[s2], __ATOMIC_RELAXED,
                                    __HIP_MEMORY_SCOPE_AGENT) >= t + 1);
          if (need3)
            g &= (__hip_atomic_load(&hslot[s3], __ATOMIC_RELAXED,
                                    __HIP_MEMORY_SCOPE_AGENT) >= t - 1);
          ok = __all(g);
          if (!ok) __builtin_amdgcn_s_sleep(1);
        }
      }
    }

    // ---------------- GEMM: DPTH-deep chunk pipeline -----------------------
    // ring bases for this step
    const f16x8* xbase = xb8 + (size_t)t * 1024;                       // layer 0
    const unsigned long long* feedbase =
        hb_u + (size_t)(((layer - 1) * 2 + (t & 1))) * 16384;          // layers 1,2
    const unsigned long long* hhbase =
        hb_u + (size_t)((layer * 2 + ((t - 1) & 1))) * 16384;

    auto loadChunk = [&](f16x8* dst, int kk) {
      if (layer == 0 && kk < 4) {
        const f16x8* bsrc = xbase + kk * 256;
#pragma unroll
        for (int bt = 0; bt < 4; ++bt) dst[bt] = bsrc[bt * 64 + lane];
      } else {
        const unsigned long long* base =
            (layer > 0 && kk < 32) ? (feedbase + (size_t)kk * 512)
                                   : (hhbase + (size_t)((layer == 0) ? (kk - 4) : (kk - 32)) * 512);
#pragma unroll
        for (int bt = 0; bt < 4; ++bt)
          dst[bt] = load_frag_agent(base + (size_t)(bt * 64 + lane) * 2);
      }
    };

    f32x4 acc[4][4];
#pragma unroll
    for (int g = 0; g < 4; ++g)
#pragma unroll
      for (int bt = 0; bt < 4; ++bt) acc[g][bt] = zacc;

    f16x8 bf[DPTH][4];
#pragma unroll
    for (int c = 0; c < DPTH; ++c)
      if (c < KW) loadChunk(bf[c], kk0 + c);
#pragma unroll
    for (int cc = 0; cc < 16; ++cc) {
      if (cc < KW) {
#pragma unroll
        for (int g = 0; g < 4; ++g)
#pragma unroll
          for (int bt = 0; bt < 4; ++bt)
            acc[g][bt] = __builtin_amdgcn_mfma_f32_16x16x32_f16(
                afrag[g][cc], bf[cc % DPTH][bt], acc[g][bt], 0, 0, 0);
        if (cc + DPTH < KW) loadChunk(bf[cc % DPTH], kk0 + cc + DPTH);
      }
    }

    // partials -> LDS  (D layout: row=q*4+r -> j, col m -> batch)
#pragma unroll
    for (int g = 0; g < 4; ++g)
#pragma unroll
      for (int bt = 0; bt < 4; ++bt)
#pragma unroll
        for (int r = 0; r < 4; ++r)
          part[wave][g][q * 4 + r][bt * 16 + m] = acc[g][bt][r];

    const bool do_fc = (layer == 2) && (t == TT - 1);
    if (do_fc && tid < 64) fcacc[tid] = 0.f;
    __syncthreads();

    // ---------------- combine: bias + gates + c/h update + publish ---------
    float pre[4][4];
#pragma unroll
    for (int g = 0; g < 4; ++g)
#pragma unroll
      for (int i = 0; i < 4; ++i) pre[g][i] = biasv[g][i];
#pragma unroll
    for (int w = 0; w < 4; ++w)
#pragma unroll
      for (int g = 0; g < 4; ++g)
#pragma unroll
        for (int i = 0; i < 4; ++i) pre[g][i] += part[w][g][j4 + i][bq];

    union { unsigned long long u; _Float16 h4[4]; } pk;
    float facc = 0.f;
#pragma unroll
    for (int i = 0; i < 4; ++i) {
      float ig = sigmf(pre[0][i]);
      float fg = sigmf(pre[1][i]);
      float gg = tanhfast(pre[2][i]);
      float og = sigmf(pre[3][i]);
      cst[i] = fg * cst[i] + ig * gg;
      float hv = og * tanhfast(cst[i]);
      pk.h4[i] = (_Float16)hv;
      facc += hv * fcwv[i];
    }
    unsigned long long* pub =
        hb_w + (((size_t)(layer * 2 + (t & 1)) * 32 + kkp) * 256 + btp * 64 + lanep) * 2 +
        slot8;
    __hip_atomic_store(pub, pk.u, __ATOMIC_RELAXED, __HIP_MEMORY_SCOPE_AGENT);

    if (do_fc) {
      atomicAdd(&fcacc[bq], facc);
      __syncthreads();
      if (tid < 64) atomicAdd(&out[tid], fcacc[tid]);
    }

    // ---------------- drain + publish flag ---------------------------------
    __builtin_amdgcn_s_waitcnt(0);  // h-stores ack'd at coherence point
    __syncthreads();                // all waves drained (and part[] reads done)
    if (tid == 0)
      __hip_atomic_store(&hslot[layer * 64 + grp], t + 1, __ATOMIC_RELAXED,
                         __HIP_MEMORY_SCOPE_AGENT);
  }
}

extern "C" void kernel_launch(void* const* d_in, const int* in_sizes, int n_in,
                              void* d_out, int out_size, void* d_ws, size_t ws_size,
                              hipStream_t stream) {
  const float* x    = (const float*)d_in[0];
  const float* Wih0 = (const float*)d_in[1];
  const float* Wih1 = (const float*)d_in[2];
  const float* Wih2 = (const float*)d_in[3];
  const float* Whh  = (const float*)d_in[4];
  const float* bih  = (const float*)d_in[5];
  const float* bhh  = (const float*)d_in[6];
  const float* fcw  = (const float*)d_in[7];
  const float* fcb  = (const float*)d_in[8];
  float* out = (float*)d_out;

  char* ws = (char*)d_ws;
  int* hslot = (int*)(ws + HSLOT_OFF);
  _Float16* hbuf = (_Float16*)(ws + HBUF_OFF);
  _Float16* xbuf = (_Float16*)(ws + XBUF_OFF);

  init_kernel<<<769, 256, 0, stream>>>((unsigned*)ws, out, fcb);
  packx_kernel<<<2048, 256, 0, stream>>>(x, xbuf);
  lstm_main<<<NBLOCKS, 256, 0, stream>>>(Wih0, Wih1, Wih2, Whh, bih, bhh, fcw,
                                         out, hslot, hbuf, xbuf);
}